// Round 8
// baseline (1784.438 us; speedup 1.0000x reference)
//
#include <hip/hip_runtime.h>
#include <hip/hip_cooperative_groups.h>
#include <cstdint>
#include <cstddef>

typedef __attribute__((ext_vector_type(8))) short short8;   // 8 bf16 (4 VGPRs) MFMA frag
typedef __attribute__((ext_vector_type(4))) float floatx4;  // MFMA accumulator

#define T_STEPS 128
#define BATCH   256
#define IDIM    512
#define HDIM    512
#define KHIST   32
#define RDEPTH  16         // h1/h2 ring depth; staleness window guarded by 8-step fences

// LDS layout sizes
#define WA_STRIDE 520      // 512 + 8 pad
#define WB_STRIDE 1032     // 1024 + 8 pad
#define LDS_BYTES 148480   // max(WB 64*1032*2 + EX 16384, WA 48*520*2 + HIST 65536)

__device__ __forceinline__ unsigned short f2bf(float x) {
  union { float f; unsigned u; } v; v.f = x;
  unsigned r = v.u + 0x7fffu + ((v.u >> 16) & 1u);   // RNE
  return (unsigned short)(r >> 16);
}
__device__ __forceinline__ float bf2f(unsigned short s) {
  union { unsigned u; float f; } v; v.u = ((unsigned)s) << 16; return v.f;
}
__device__ __forceinline__ float sigm(float x) { return 1.0f / (1.0f + __expf(-x)); }
__device__ __forceinline__ float tanh_f(float x) {
  float ax = fabsf(x);
  float e = __expf(-2.0f * ax);
  float t = (1.0f - e) / (1.0f + e);
  return x < 0.0f ? -t : t;
}

// ---- protocol helpers ----
// Producers write shared data with sc0 sc1 (write-through to LLC, no dirty L2
// lines anywhere). Consumers read with PLAIN cached loads (L1+L2 fill -> XCD
// sharing). Staleness of cached lines across ring-slot reuse (period RDEPTH=16)
// is killed by an agent acquire fence (L1+L2 inv) every 8 steps. Flags stay
// fully uncached (sc0 sc1 both directions).

__device__ __forceinline__ void llc_store_4rows(unsigned short* p,
                                                unsigned short a, unsigned short b,
                                                unsigned short c, unsigned short d) {
  asm volatile(
    "global_store_short %4, %0, off sc0 sc1\n\t"
    "global_store_short %4, %1, off offset:1024 sc0 sc1\n\t"
    "global_store_short %4, %2, off offset:2048 sc0 sc1\n\t"
    "global_store_short %4, %3, off offset:3072 sc0 sc1"
    :: "v"((unsigned)a), "v"((unsigned)b), "v"((unsigned)c), "v"((unsigned)d), "v"(p)
    : "memory");
}
__device__ __forceinline__ int flag_ld_llc(const int* p) {
  int v; asm volatile("global_load_dword %0, %1, off sc0 sc1\n\ts_waitcnt vmcnt(0)"
                      : "=v"(v) : "v"(p) : "memory"); return v;
}
__device__ __forceinline__ void flag_st_llc(int* p, int v) {
  asm volatile("global_store_dword %0, %1, off sc0 sc1" :: "v"(p), "v"(v) : "memory");
}
__device__ __forceinline__ void drain_vm() {
  asm volatile("s_waitcnt vmcnt(0)" ::: "memory");
}

// ---------------- prep kernels ----------------

__global__ void cast4_kernel(const float* __restrict__ src, unsigned short* __restrict__ dst, int n4) {
  int i = blockIdx.x * blockDim.x + threadIdx.x;
  if (i >= n4) return;
  float4 v = reinterpret_cast<const float4*>(src)[i];
  ushort4 o;
  o.x = f2bf(v.x); o.y = f2bf(v.y); o.z = f2bf(v.z); o.w = f2bf(v.w);
  reinterpret_cast<ushort4*>(dst)[i] = o;
}

__global__ void pack_w2_kernel(const float* __restrict__ Wih, const float* __restrict__ Whh,
                               unsigned short* __restrict__ W2) {
  int i4 = blockIdx.x * blockDim.x + threadIdx.x;   // over 2048*1024/4
  if (i4 >= (2048 * 1024 / 4)) return;
  int i = i4 * 4; int n = i >> 10; int k = i & 1023;
  float4 v = (k < 512) ? reinterpret_cast<const float4*>(Wih + n * 512 + k)[0]
                       : reinterpret_cast<const float4*>(Whh + n * 512 + (k - 512))[0];
  ushort4 o;
  o.x = f2bf(v.x); o.y = f2bf(v.y); o.z = f2bf(v.z); o.w = f2bf(v.w);
  reinterpret_cast<ushort4*>(W2 + i)[0] = o;
}

__global__ void prep_misc_kernel(const float* __restrict__ b_d,
                                 const float* __restrict__ b_mih, const float* __restrict__ b_mhh,
                                 const float* __restrict__ b_ih,  const float* __restrict__ b_hh,
                                 float* __restrict__ wd2, float* __restrict__ bA, float* __restrict__ bB) {
  int tid = threadIdx.x;  // 1024 threads, 1 block
  if (tid < HDIM) {
    float d = 0.5f * sigm(b_d[tid]);
    float c = 1.0f;
    for (int i = 0; i < KHIST; ++i) {
      c *= ((float)i - d) / ((float)i + 1.0f);
      wd2[i * HDIM + tid] = c;          // wd2[j-1] = c_j
    }
  }
  for (int n = tid; n < 3 * HDIM; n += 1024) bA[n] = b_mih[n] + b_mhh[n];
  for (int n = tid; n < 4 * HDIM; n += 1024) bB[n] = b_ih[n] + b_hh[n];
}

// ---------------- big input-projection GEMM (fp32 out) ----------------
__global__ __launch_bounds__(256) void gx_gemm_kernel(const unsigned short* __restrict__ Xb,
                                                      const unsigned short* __restrict__ Wb,
                                                      const float* __restrict__ bA,
                                                      float* __restrict__ GX) {
  const int lane = threadIdx.x & 63;
  const int wave = threadIdx.x >> 6;
  const int q = lane >> 4, r16 = lane & 15;
  const int m0 = blockIdx.y * 64 + wave * 16;
  const int n0 = blockIdx.x * 64;
  floatx4 acc[4];
  #pragma unroll
  for (int i = 0; i < 4; ++i) acc[i] = (floatx4){0.f, 0.f, 0.f, 0.f};
  const unsigned short* arow = Xb + (size_t)(m0 + r16) * IDIM;
  #pragma unroll 4
  for (int k0 = 0; k0 < IDIM; k0 += 32) {
    short8 a = *(const short8*)(arow + k0 + q * 8);
    #pragma unroll
    for (int nt = 0; nt < 4; ++nt) {
      short8 b = *(const short8*)(Wb + (size_t)(n0 + nt * 16 + r16) * IDIM + k0 + q * 8);
      acc[nt] = __builtin_amdgcn_mfma_f32_16x16x32_bf16(a, b, acc[nt], 0, 0, 0);
    }
  }
  #pragma unroll
  for (int nt = 0; nt < 4; ++nt) {
    int col = n0 + nt * 16 + r16;
    float bias = bA[col];
    #pragma unroll
    for (int j = 0; j < 4; ++j) {
      int row = m0 + q * 4 + j;
      GX[(size_t)row * 1536 + col] = acc[nt][j] + bias;
    }
  }
}

// ---------------- async persistent recurrent kernel ----------------
// Round-6 proven layout: 256 blocks, xcd=blk&7 -> chain bs=xcd>>1, role A/B by
// parity, hs=blk>>3. Per-wave flag polling (no entry barrier); filter + GX
// prefetch before the poll; cached-read/write-through exchange (see helpers).
__global__ __launch_bounds__(512, 1) void recurrent2(
    const float* __restrict__ GX,              // (T*256 x 1536) fp32
    const unsigned short* __restrict__ Wmhh,   // (1536 x 512) bf16 N-major
    const unsigned short* __restrict__ W2,     // (2048 x 1024) bf16 N-major
    const float* __restrict__ bB,              // (2048)
    const float* __restrict__ wd2,             // (32 x 512)
    unsigned short* __restrict__ h1his,        // (16 x 256 x 512) bf16 h1 ring
    unsigned short* __restrict__ h2his,        // (16 x 256 x 512) bf16 h2 ring
    float* __restrict__ sel,                   // (256 x 512) fp32
    const int* __restrict__ length,
    int* __restrict__ counters) {              // aFlags at bs*64, bFlags at 1024+bs*64
  extern __shared__ char lds[];
  const int tid = threadIdx.x;
  const int lane = tid & 63;
  const int wv = tid >> 6;                 // 0..7
  const int q = lane >> 4, r16 = lane & 15;
  const int xcd = (int)blockIdx.x & 7;
  const int bs = xcd >> 1;
  const bool isA = (xcd & 1) == 0;
  const int hs = (int)blockIdx.x >> 3;
  const int hcol = hs * 16 + r16;
  int* aFlags = counters + bs * 64;            // 32 ints used, 256B group spacing
  int* bFlags = counters + 1024 + bs * 64;

  if (isA) {
    unsigned short* WA = (unsigned short*)lds;                        // [48][520]
    unsigned short* HI = (unsigned short*)(lds + 48 * WA_STRIDE * 2); // hist [32][16 rg][16 c][4 j]
    for (int idx = tid; idx < 48 * 64; idx += 512) {
      int rowi = idx >> 6, kc = idx & 63;
      int g = rowi >> 4, c = rowi & 15;
      const unsigned short* src = Wmhh + ((size_t)(g * 512 + hs * 16 + c)) * 512 + kc * 8;
      *(short8*)(WA + rowi * WA_STRIDE + kc * 8) = *(const short8*)src;
    }
    for (int idx = tid; idx < 4096; idx += 512)        // zero hist (64KB)
      ((uint4*)HI)[idx] = (uint4){0, 0, 0, 0};
    float wdr[KHIST];
    #pragma unroll
    for (int l = 0; l < KHIST; ++l) wdr[l] = wd2[l * HDIM + hcol];
    __syncthreads();

    const int mi = wv & 3;
    const int m0 = bs * 64 + mi * 16;
    const int rg = mi * 4 + q;

    for (int s = 0; s < T_STEPS; ++s) {
      if ((s & 7) == 0)   // kill any cached exchange lines older than one ring period
        __builtin_amdgcn_fence(__ATOMIC_ACQUIRE, "agent");
      float gx0[4], gx1[4], gx2[4], fj[4];
      if (wv < 4) {
        // GX prefetch (cached loads; complete during the poll)
        #pragma unroll
        for (int j = 0; j < 4; ++j) {
          int row = m0 + q * 4 + j;
          size_t gidx = ((size_t)s * BATCH + row) * 1536 + hcol;
          gx0[j] = GX[gidx];
          gx1[j] = GX[gidx + 512];
          gx2[j] = GX[gidx + 1024];
        }
        // frac-diff filter: block-local, moved BEFORE the wait
        float f0 = 0.f, f1 = 0.f, f2 = 0.f, f3 = 0.f;
        #pragma unroll
        for (int jj = 1; jj <= KHIST; ++jj) {
          int sl = (s - jj) & (KHIST - 1);
          ushort4 hv = *(const ushort4*)(HI + ((size_t)(sl * 16 + rg) * 16 + r16) * 4);
          float wc = wdr[jj - 1];
          f0 += wc * bf2f(hv.x); f1 += wc * bf2f(hv.y);
          f2 += wc * bf2f(hv.z); f3 += wc * bf2f(hv.w);
        }
        fj[0] = f0; fj[1] = f1; fj[2] = f2; fj[3] = f3;
        // per-wave poll (no entry barrier)
        if (s > 0) {
          if (lane < 32) {
            const int* f = aFlags + lane;
            while (flag_ld_llc(f) < s) __builtin_amdgcn_s_sleep(1);
          } else {
            int tgt = s - (RDEPTH - 1);                 // ring-slot free (B side)
            if (tgt > 0) {
              const int* f = bFlags + (lane - 32);
              while (flag_ld_llc(f) < tgt) __builtin_amdgcn_s_sleep(1);
            }
          }
        }
        floatx4 acc[3];
        #pragma unroll
        for (int g = 0; g < 3; ++g) acc[g] = (floatx4){0.f, 0.f, 0.f, 0.f};
        if (s > 0) {
          const unsigned short* ab = h1his +
              ((size_t)((s - 1) & (RDEPTH - 1)) * BATCH + m0 + r16) * 512 + q * 8;
          short8 af[16];
          #pragma unroll
          for (int kk = 0; kk < 16; ++kk) af[kk] = *(const short8*)(ab + kk * 32);
          #pragma unroll
          for (int kk = 0; kk < 16; ++kk) {
            #pragma unroll
            for (int g = 0; g < 3; ++g) {
              short8 b = *(const short8*)(WA + (size_t)(g * 16 + r16) * WA_STRIDE + kk * 32 + q * 8);
              acc[g] = __builtin_amdgcn_mfma_f32_16x16x32_bf16(af[kk], b, acc[g], 0, 0, 0);
            }
          }
        }
        float c1[4];
        unsigned short h1w[4];
        #pragma unroll
        for (int j = 0; j < 4; ++j) {
          float gI = gx0[j] + acc[0][j];
          float gO = gx1[j] + acc[1][j];
          float gG = gx2[j] + acc[2][j];
          float ig = sigm(gI), og = sigm(gO), cd = tanh_f(gG);
          float c1v = ig * cd - fj[j];
          c1[j] = c1v;
          h1w[j] = f2bf(og * tanh_f(c1v));
        }
        llc_store_4rows(h1his + ((size_t)(s & (RDEPTH - 1)) * BATCH + m0 + q * 4) * 512 + hcol,
                        h1w[0], h1w[1], h1w[2], h1w[3]);
        ushort4 hw;
        hw.x = f2bf(c1[0]); hw.y = f2bf(c1[1]); hw.z = f2bf(c1[2]); hw.w = f2bf(c1[3]);
        *(ushort4*)(HI + ((size_t)((s & (KHIST - 1)) * 16 + rg) * 16 + r16) * 4) = hw;
      }
      drain_vm();        // per-wave: publish acked at LLC before barrier
      __syncthreads();
      if (tid == 0)
        flag_st_llc(aFlags + hs, s + 1);
    }
  } else {
    // ---- B block ----
    unsigned short* WB = (unsigned short*)lds;                 // [64][1032]
    float* EX = (float*)(lds + 64 * WB_STRIDE * 2);            // exch [4 mi][4 g][64 lane][4]
    for (int idx = tid; idx < 64 * 128; idx += 512) {
      int rowi = idx >> 7, kc = idx & 127;
      int g = rowi >> 4, c = rowi & 15;
      const unsigned short* src = W2 + ((size_t)(g * 512 + hs * 16 + c)) * 1024 + kc * 8;
      *(short8*)(WB + rowi * WB_STRIDE + kc * 8) = *(const short8*)src;
    }
    const int mi = wv >> 1, kh = wv & 1;
    const int m0 = bs * 64 + mi * 16;
    float c2r[4] = {0.f, 0.f, 0.f, 0.f};
    int lenr[4];
    float bBr[4];
    #pragma unroll
    for (int j = 0; j < 4; ++j) lenr[j] = length[m0 + q * 4 + j];
    #pragma unroll
    for (int g = 0; g < 4; ++g) bBr[g] = bB[g * 512 + hcol];
    __syncthreads();

    for (int t = 0; t < T_STEPS; ++t) {
      if ((t & 7) == 0)
        __builtin_amdgcn_fence(__ATOMIC_ACQUIRE, "agent");
      // per-wave poll
      if (lane < 32) {
        const int* f = aFlags + lane;
        while (flag_ld_llc(f) < t + 1) __builtin_amdgcn_s_sleep(1);   // A done t
      } else if (t > 0) {
        const int* f = bFlags + (lane - 32);
        while (flag_ld_llc(f) < t) __builtin_amdgcn_s_sleep(1);       // B peers done t-1
      }
      floatx4 acc[4];
      #pragma unroll
      for (int g = 0; g < 4; ++g) acc[g] = (floatx4){0.f, 0.f, 0.f, 0.f};
      bool doit = !(kh == 1 && t == 0);
      if (doit) {
        const unsigned short* ab;
        if (kh == 0)
          ab = h1his + ((size_t)(t & (RDEPTH - 1)) * BATCH + m0 + r16) * 512 + q * 8;
        else
          ab = h2his + ((size_t)((t - 1) & (RDEPTH - 1)) * BATCH + m0 + r16) * 512 + q * 8;
        short8 af[16];
        #pragma unroll
        for (int kk = 0; kk < 16; ++kk) af[kk] = *(const short8*)(ab + kk * 32);
        #pragma unroll
        for (int kk = 0; kk < 16; ++kk) {
          #pragma unroll
          for (int g = 0; g < 4; ++g) {
            short8 b = *(const short8*)(WB + (size_t)(g * 16 + r16) * WB_STRIDE + kh * 512 + kk * 32 + q * 8);
            acc[g] = __builtin_amdgcn_mfma_f32_16x16x32_bf16(af[kk], b, acc[g], 0, 0, 0);
          }
        }
      }
      if (kh == 1) {
        #pragma unroll
        for (int g = 0; g < 4; ++g)
          *(floatx4*)(EX + ((size_t)(mi * 4 + g) * 64 + lane) * 4) = acc[g];
      }
      __syncthreads();
      if (kh == 0) {
        #pragma unroll
        for (int g = 0; g < 4; ++g)
          acc[g] += *(const floatx4*)(EX + ((size_t)(mi * 4 + g) * 64 + lane) * 4);
        unsigned short h2w[4];
        #pragma unroll
        for (int j = 0; j < 4; ++j) {
          int row = m0 + q * 4 + j;
          float gi = acc[0][j] + bBr[0];
          float gf = acc[1][j] + bBr[1];
          float gg = acc[2][j] + bBr[2];
          float go = acc[3][j] + bBr[3];
          float c2n = sigm(gf) * c2r[j] + sigm(gi) * tanh_f(gg);
          c2r[j] = c2n;
          float h2n = tanh_f(sigm(go) * tanh_f(c2n));
          h2w[j] = f2bf(h2n);
          if (lenr[j] == t) sel[(size_t)row * 512 + hcol] = h2n;
        }
        llc_store_4rows(h2his + ((size_t)(t & (RDEPTH - 1)) * BATCH + m0 + q * 4) * 512 + hcol,
                        h2w[0], h2w[1], h2w[2], h2w[3]);
      }
      drain_vm();
      __syncthreads();
      if (tid == 0)
        flag_st_llc(bFlags + hs, t + 1);
    }
  }
}

// ---------------- output head ----------------
__global__ void out_head_kernel(const float* __restrict__ sel, const float* __restrict__ Wout,
                                const float* __restrict__ bout, float* __restrict__ out) {
  int b = blockIdx.x, lane = threadIdx.x;   // 256 blocks x 64 threads
  float acc[5] = {0.f, 0.f, 0.f, 0.f, 0.f};
  for (int j = lane; j < HDIM; j += 64) {
    float x = sel[(size_t)b * HDIM + j];
    #pragma unroll
    for (int o = 0; o < 5; ++o) acc[o] += x * Wout[o * HDIM + j];
  }
  #pragma unroll
  for (int o = 0; o < 5; ++o)
    for (int off = 32; off > 0; off >>= 1) acc[o] += __shfl_down(acc[o], off);
  if (lane == 0) {
    float v[5]; float m = -1e30f;
    #pragma unroll
    for (int o = 0; o < 5; ++o) { v[o] = acc[o] + bout[o]; m = fmaxf(m, v[o]); }
    float s = 0.f;
    #pragma unroll
    for (int o = 0; o < 5; ++o) s += __expf(v[o] - m);
    float l = logf(s) + m;
    #pragma unroll
    for (int o = 0; o < 5; ++o) out[b * 5 + o] = v[o] - l;
  }
}

// ---------------- launch ----------------
extern "C" void kernel_launch(void* const* d_in, const int* in_sizes, int n_in,
                              void* d_out, int out_size, void* d_ws, size_t ws_size,
                              hipStream_t stream) {
  const float* x      = (const float*)d_in[0];
  const int*   length = (const int*)d_in[1];
  const float* b_d    = (const float*)d_in[2];
  const float* W_mih  = (const float*)d_in[3];
  const float* W_mhh  = (const float*)d_in[4];
  const float* b_mih  = (const float*)d_in[5];
  const float* b_mhh  = (const float*)d_in[6];
  const float* W_ih   = (const float*)d_in[7];
  const float* W_hh   = (const float*)d_in[8];
  const float* b_ih   = (const float*)d_in[9];
  const float* b_hh   = (const float*)d_in[10];
  const float* W_out  = (const float*)d_in[11];
  const float* b_out  = (const float*)d_in[12];
  float* out = (float*)d_out;

  char* ws = (char*)d_ws;
  size_t off = 0;
  auto take = [&](size_t bytes) -> char* {
    char* p = ws + off;
    off += (bytes + 255) & ~(size_t)255;
    return p;
  };

  unsigned short* Xb     = (unsigned short*)take((size_t)T_STEPS * BATCH * IDIM * 2);
  unsigned short* Wmih_b = (unsigned short*)take(1536 * 512 * 2);
  unsigned short* Wmhh_b = (unsigned short*)take(1536 * 512 * 2);
  unsigned short* W2_b   = (unsigned short*)take(2048 * 1024 * 2);
  float* bA  = (float*)take(1536 * 4);
  float* bB  = (float*)take(2048 * 4);
  float* wd2 = (float*)take(KHIST * HDIM * 4);
  unsigned short* h1his = (unsigned short*)take((size_t)RDEPTH * BATCH * 512 * 2);  // 4 MiB
  unsigned short* h2his = (unsigned short*)take((size_t)RDEPTH * BATCH * 512 * 2);  // 4 MiB
  float* sel = (float*)take((size_t)BATCH * HDIM * 4);
  int* counters = (int*)take(8192);           // aFlags at bs*64 ints, bFlags at 1024+bs*64 ints
  float* GX = (float*)take((size_t)T_STEPS * BATCH * 1536 * 4);
  if (off > ws_size) return;  // workspace too small -> loud validation failure

  hipMemsetAsync(counters, 0, 8192, stream);
  prep_misc_kernel<<<1, 1024, 0, stream>>>(b_d, b_mih, b_mhh, b_ih, b_hh, wd2, bA, bB);
  cast4_kernel<<<(T_STEPS * BATCH * IDIM / 4 + 255) / 256, 256, 0, stream>>>(x, Xb, T_STEPS * BATCH * IDIM / 4);
  cast4_kernel<<<(1536 * 512 / 4 + 255) / 256, 256, 0, stream>>>(W_mih, Wmih_b, 1536 * 512 / 4);
  cast4_kernel<<<(1536 * 512 / 4 + 255) / 256, 256, 0, stream>>>(W_mhh, Wmhh_b, 1536 * 512 / 4);
  pack_w2_kernel<<<(2048 * 1024 / 4 + 255) / 256, 256, 0, stream>>>(W_ih, W_hh, W2_b);
  gx_gemm_kernel<<<dim3(1536 / 64, T_STEPS * BATCH / 64), 256, 0, stream>>>(Xb, Wmih_b, bA, GX);

  hipFuncSetAttribute((const void*)recurrent2, hipFuncAttributeMaxDynamicSharedMemorySize, LDS_BYTES);
  void* kargs[] = { (void*)&GX, (void*)&Wmhh_b, (void*)&W2_b, (void*)&bB, (void*)&wd2,
                    (void*)&h1his, (void*)&h2his, (void*)&sel, (void*)&length,
                    (void*)&counters };
  hipLaunchCooperativeKernel((void*)recurrent2, dim3(256), dim3(512), kargs, LDS_BYTES, stream);

  out_head_kernel<<<BATCH, 64, 0, stream>>>(sel, W_out, b_out, out);
}

// Round 9
// 1670.570 us; speedup vs baseline: 1.0682x; 1.0682x over previous
//
#include <hip/hip_runtime.h>
#include <hip/hip_cooperative_groups.h>
#include <cstdint>
#include <cstddef>

typedef __attribute__((ext_vector_type(8))) short short8;   // 8 bf16 (4 VGPRs) MFMA frag
typedef __attribute__((ext_vector_type(4))) float floatx4;  // MFMA accumulator

#define T_STEPS 128
#define BATCH   256
#define IDIM    512
#define HDIM    512
#define KHIST   32
#define RDEPTH  16

// LDS layout
#define WA_STRIDE 520      // 512 + 8 pad
#define WB_STRIDE 1032     // 1024 + 8 pad
#define LDS_BYTES 148480   // B: WB 64*1032*2 + EX 16384 = 148480; A: 49920+65536+ctr

__device__ __forceinline__ unsigned short f2bf(float x) {
  union { float f; unsigned u; } v; v.f = x;
  unsigned r = v.u + 0x7fffu + ((v.u >> 16) & 1u);   // RNE
  return (unsigned short)(r >> 16);
}
__device__ __forceinline__ float bf2f(unsigned short s) {
  union { unsigned u; float f; } v; v.u = ((unsigned)s) << 16; return v.f;
}
__device__ __forceinline__ float sigm(float x) { return 1.0f / (1.0f + __expf(-x)); }
__device__ __forceinline__ float tanh_f(float x) {
  float ax = fabsf(x);
  float e = __expf(-2.0f * ax);
  float t = (1.0f - e) / (1.0f + e);
  return x < 0.0f ? -t : t;
}

// ---- LLC-coherent exchange (round-6 proven protocol, no fences) ----
__device__ __forceinline__ void llc_load_1k(const unsigned short* p, short8* r) {
  asm volatile(
    "global_load_dwordx4 %0,  %16, off sc0 sc1\n\t"
    "global_load_dwordx4 %1,  %16, off offset:64 sc0 sc1\n\t"
    "global_load_dwordx4 %2,  %16, off offset:128 sc0 sc1\n\t"
    "global_load_dwordx4 %3,  %16, off offset:192 sc0 sc1\n\t"
    "global_load_dwordx4 %4,  %16, off offset:256 sc0 sc1\n\t"
    "global_load_dwordx4 %5,  %16, off offset:320 sc0 sc1\n\t"
    "global_load_dwordx4 %6,  %16, off offset:384 sc0 sc1\n\t"
    "global_load_dwordx4 %7,  %16, off offset:448 sc0 sc1\n\t"
    "global_load_dwordx4 %8,  %16, off offset:512 sc0 sc1\n\t"
    "global_load_dwordx4 %9,  %16, off offset:576 sc0 sc1\n\t"
    "global_load_dwordx4 %10, %16, off offset:640 sc0 sc1\n\t"
    "global_load_dwordx4 %11, %16, off offset:704 sc0 sc1\n\t"
    "global_load_dwordx4 %12, %16, off offset:768 sc0 sc1\n\t"
    "global_load_dwordx4 %13, %16, off offset:832 sc0 sc1\n\t"
    "global_load_dwordx4 %14, %16, off offset:896 sc0 sc1\n\t"
    "global_load_dwordx4 %15, %16, off offset:960 sc0 sc1\n\t"
    "s_waitcnt vmcnt(0)"
    : "=&v"(r[0]), "=&v"(r[1]), "=&v"(r[2]), "=&v"(r[3]),
      "=&v"(r[4]), "=&v"(r[5]), "=&v"(r[6]), "=&v"(r[7]),
      "=&v"(r[8]), "=&v"(r[9]), "=&v"(r[10]), "=&v"(r[11]),
      "=&v"(r[12]), "=&v"(r[13]), "=&v"(r[14]), "=&v"(r[15])
    : "v"(p)
    : "memory");
}
__device__ __forceinline__ void llc_store_4rows(unsigned short* p,
                                                unsigned short a, unsigned short b,
                                                unsigned short c, unsigned short d) {
  asm volatile(
    "global_store_short %4, %0, off sc0 sc1\n\t"
    "global_store_short %4, %1, off offset:1024 sc0 sc1\n\t"
    "global_store_short %4, %2, off offset:2048 sc0 sc1\n\t"
    "global_store_short %4, %3, off offset:3072 sc0 sc1"
    :: "v"((unsigned)a), "v"((unsigned)b), "v"((unsigned)c), "v"((unsigned)d), "v"(p)
    : "memory");
}
__device__ __forceinline__ int flag_ld_llc(const int* p) {
  int v; asm volatile("global_load_dword %0, %1, off sc0 sc1\n\ts_waitcnt vmcnt(0)"
                      : "=v"(v) : "v"(p) : "memory"); return v;
}
__device__ __forceinline__ void flag_st_llc(int* p, int v) {
  asm volatile("global_store_dword %0, %1, off sc0 sc1" :: "v"(p), "v"(v) : "memory");
}
__device__ __forceinline__ void drain_vm() {
  asm volatile("s_waitcnt vmcnt(0)" ::: "memory");
}

// ---------------- single fused prep kernel ----------------
// blocks [0,16384): cast x -> Xb            (4,194,304 quads)
// blocks [16384,17152): cast W_mih          (196,608 quads)
// blocks [17152,17920): cast W_mhh          (196,608 quads)
// blocks [17920,19968): pack [W_ih;W_hh]    (524,288 quads)
// blocks [19968,19984): wd2 / bA / bB
// blocks [19984,19992): zero counters (2048 ints)
#define PREP_BLOCKS 19992
__global__ __launch_bounds__(256) void prep_all(
    const float* __restrict__ x, const float* __restrict__ Wmih, const float* __restrict__ Wmhh,
    const float* __restrict__ Wih, const float* __restrict__ Whh,
    const float* __restrict__ b_d, const float* __restrict__ b_mih, const float* __restrict__ b_mhh,
    const float* __restrict__ b_ih, const float* __restrict__ b_hh,
    unsigned short* __restrict__ Xb, unsigned short* __restrict__ Wmih_b,
    unsigned short* __restrict__ Wmhh_b, unsigned short* __restrict__ W2,
    float* __restrict__ wd2, float* __restrict__ bA, float* __restrict__ bB,
    int* __restrict__ counters) {
  const int blk = blockIdx.x, tid = threadIdx.x;
  if (blk < 16384) {
    int i = blk * 256 + tid;
    float4 v = reinterpret_cast<const float4*>(x)[i];
    ushort4 o; o.x = f2bf(v.x); o.y = f2bf(v.y); o.z = f2bf(v.z); o.w = f2bf(v.w);
    reinterpret_cast<ushort4*>(Xb)[i] = o;
  } else if (blk < 17152) {
    int i = (blk - 16384) * 256 + tid;
    float4 v = reinterpret_cast<const float4*>(Wmih)[i];
    ushort4 o; o.x = f2bf(v.x); o.y = f2bf(v.y); o.z = f2bf(v.z); o.w = f2bf(v.w);
    reinterpret_cast<ushort4*>(Wmih_b)[i] = o;
  } else if (blk < 17920) {
    int i = (blk - 17152) * 256 + tid;
    float4 v = reinterpret_cast<const float4*>(Wmhh)[i];
    ushort4 o; o.x = f2bf(v.x); o.y = f2bf(v.y); o.z = f2bf(v.z); o.w = f2bf(v.w);
    reinterpret_cast<ushort4*>(Wmhh_b)[i] = o;
  } else if (blk < 19968) {
    int i4 = (blk - 17920) * 256 + tid;
    int i = i4 * 4; int n = i >> 10; int k = i & 1023;
    float4 v = (k < 512) ? reinterpret_cast<const float4*>(Wih + n * 512 + k)[0]
                         : reinterpret_cast<const float4*>(Whh + n * 512 + (k - 512))[0];
    ushort4 o; o.x = f2bf(v.x); o.y = f2bf(v.y); o.z = f2bf(v.z); o.w = f2bf(v.w);
    reinterpret_cast<ushort4*>(W2 + i)[0] = o;
  } else if (blk < 19984) {
    int t = (blk - 19968) * 256 + tid;
    if (t < 512) {
      float d = 0.5f * sigm(b_d[t]);
      float c = 1.0f;
      for (int i = 0; i < KHIST; ++i) {
        c *= ((float)i - d) / ((float)i + 1.0f);
        wd2[i * HDIM + t] = c;
      }
    } else if (t < 2048) {
      int n = t - 512;
      bA[n] = b_mih[n] + b_mhh[n];
    } else {
      int n = t - 2048;
      bB[n] = b_ih[n] + b_hh[n];
    }
  } else {
    int i = (blk - 19984) * 256 + tid;
    counters[i] = 0;
  }
}

// ---------------- input-projection GEMM (bf16 out) ----------------
__global__ __launch_bounds__(256) void gx_gemm_kernel(const unsigned short* __restrict__ Xb,
                                                      const unsigned short* __restrict__ Wb,
                                                      const float* __restrict__ bA,
                                                      unsigned short* __restrict__ GXh) {
  const int lane = threadIdx.x & 63;
  const int wave = threadIdx.x >> 6;
  const int q = lane >> 4, r16 = lane & 15;
  const int m0 = blockIdx.y * 64 + wave * 16;
  const int n0 = blockIdx.x * 64;
  floatx4 acc[4];
  #pragma unroll
  for (int i = 0; i < 4; ++i) acc[i] = (floatx4){0.f, 0.f, 0.f, 0.f};
  const unsigned short* arow = Xb + (size_t)(m0 + r16) * IDIM;
  #pragma unroll 4
  for (int k0 = 0; k0 < IDIM; k0 += 32) {
    short8 a = *(const short8*)(arow + k0 + q * 8);
    #pragma unroll
    for (int nt = 0; nt < 4; ++nt) {
      short8 b = *(const short8*)(Wb + (size_t)(n0 + nt * 16 + r16) * IDIM + k0 + q * 8);
      acc[nt] = __builtin_amdgcn_mfma_f32_16x16x32_bf16(a, b, acc[nt], 0, 0, 0);
    }
  }
  #pragma unroll
  for (int nt = 0; nt < 4; ++nt) {
    int col = n0 + nt * 16 + r16;
    float bias = bA[col];
    #pragma unroll
    for (int j = 0; j < 4; ++j) {
      int row = m0 + q * 4 + j;
      GXh[(size_t)row * 1536 + col] = f2bf(acc[nt][j] + bias);
    }
  }
}

// ---------------- async persistent recurrent kernel ----------------
// Round-6 protocol (sc0sc1 exchange, relaxed flag stores, no fences) with:
//  - A blocks barrier-FREE in steady state (hist is wave-private): 4 work
//    waves run independently; LDS done-counter releases the flag as soon as
//    the 4th wave drains. Idle waves (wv>=4) exit after init.
//  - per-wave polling everywhere (no single-wave poll + barrier propagation)
//  - GX in bf16 (half the HBM fetch), RDEPTH=16 rings
__global__ __launch_bounds__(512, 1) void recurrent2(
    const unsigned short* __restrict__ GXh,    // (T*256 x 1536) bf16
    const unsigned short* __restrict__ Wmhh,   // (1536 x 512) bf16 N-major
    const unsigned short* __restrict__ W2,     // (2048 x 1024) bf16 N-major
    const float* __restrict__ bB,              // (2048)
    const float* __restrict__ wd2,             // (32 x 512)
    unsigned short* __restrict__ h1his,        // (16 x 256 x 512) bf16
    unsigned short* __restrict__ h2his,        // (16 x 256 x 512) bf16
    float* __restrict__ sel,                   // (256 x 512) fp32
    const int* __restrict__ length,
    int* __restrict__ counters) {              // aFlags at bs*64, bFlags at 1024+bs*64
  extern __shared__ char lds[];
  const int tid = threadIdx.x;
  const int lane = tid & 63;
  const int wv = tid >> 6;                 // 0..7
  const int q = lane >> 4, r16 = lane & 15;
  const int xcd = (int)blockIdx.x & 7;
  const int bs = xcd >> 1;
  const bool isA = (xcd & 1) == 0;
  const int hs = (int)blockIdx.x >> 3;
  const int hcol = hs * 16 + r16;
  int* aFlags = counters + bs * 64;
  int* bFlags = counters + 1024 + bs * 64;

  if (isA) {
    unsigned short* WA = (unsigned short*)lds;                        // [48][520]
    unsigned short* HI = (unsigned short*)(lds + 48 * WA_STRIDE * 2); // 64KB hist
    int* dctr = (int*)(lds + 48 * WA_STRIDE * 2 + 65536);             // done counter
    for (int idx = tid; idx < 48 * 64; idx += 512) {
      int rowi = idx >> 6, kc = idx & 63;
      int g = rowi >> 4, c = rowi & 15;
      const unsigned short* src = Wmhh + ((size_t)(g * 512 + hs * 16 + c)) * 512 + kc * 8;
      *(short8*)(WA + rowi * WA_STRIDE + kc * 8) = *(const short8*)src;
    }
    for (int idx = tid; idx < 4096; idx += 512)
      ((uint4*)HI)[idx] = (uint4){0, 0, 0, 0};
    if (tid == 0) *dctr = 0;
    __syncthreads();
    if (wv >= 4) return;                   // idle waves gone; no barriers below

    float wdr[KHIST];
    #pragma unroll
    for (int l = 0; l < KHIST; ++l) wdr[l] = wd2[l * HDIM + hcol];
    const int mi = wv;
    const int m0 = bs * 64 + mi * 16;
    const int rg = mi * 4 + q;

    for (int s = 0; s < T_STEPS; ++s) {
      // GX prefetch (bf16, issue before poll; converted after)
      unsigned short gu[12];
      #pragma unroll
      for (int j = 0; j < 4; ++j) {
        int row = m0 + q * 4 + j;
        size_t gidx = ((size_t)s * BATCH + row) * 1536 + hcol;
        gu[j]     = GXh[gidx];
        gu[4 + j] = GXh[gidx + 512];
        gu[8 + j] = GXh[gidx + 1024];
      }
      // frac-diff filter (wave-private LDS)
      float f0 = 0.f, f1 = 0.f, f2 = 0.f, f3 = 0.f;
      #pragma unroll
      for (int jj = 1; jj <= KHIST; ++jj) {
        int sl = (s - jj) & (KHIST - 1);
        ushort4 hv = *(const ushort4*)(HI + ((size_t)(sl * 16 + rg) * 16 + r16) * 4);
        float wc = wdr[jj - 1];
        f0 += wc * bf2f(hv.x); f1 += wc * bf2f(hv.y);
        f2 += wc * bf2f(hv.z); f3 += wc * bf2f(hv.w);
      }
      float fj[4] = {f0, f1, f2, f3};
      // per-wave poll
      if (s > 0) {
        if (lane < 32) {
          const int* f = aFlags + lane;
          while (flag_ld_llc(f) < s) __builtin_amdgcn_s_sleep(1);
        } else {
          int tgt = s - (RDEPTH - 1);
          if (tgt > 0) {
            const int* f = bFlags + (lane - 32);
            while (flag_ld_llc(f) < tgt) __builtin_amdgcn_s_sleep(1);
          }
        }
      }
      floatx4 acc[3];
      #pragma unroll
      for (int g = 0; g < 3; ++g) acc[g] = (floatx4){0.f, 0.f, 0.f, 0.f};
      if (s > 0) {
        const unsigned short* ab = h1his +
            ((size_t)((s - 1) & (RDEPTH - 1)) * BATCH + m0 + r16) * 512 + q * 8;
        short8 af[16];
        llc_load_1k(ab, af);
        #pragma unroll
        for (int kk = 0; kk < 16; ++kk) {
          #pragma unroll
          for (int g = 0; g < 3; ++g) {
            short8 b = *(const short8*)(WA + (size_t)(g * 16 + r16) * WA_STRIDE + kk * 32 + q * 8);
            acc[g] = __builtin_amdgcn_mfma_f32_16x16x32_bf16(af[kk], b, acc[g], 0, 0, 0);
          }
        }
      }
      float c1[4];
      unsigned short h1w[4];
      #pragma unroll
      for (int j = 0; j < 4; ++j) {
        float gI = bf2f(gu[j])     + acc[0][j];
        float gO = bf2f(gu[4 + j]) + acc[1][j];
        float gG = bf2f(gu[8 + j]) + acc[2][j];
        float ig = sigm(gI), og = sigm(gO), cd = tanh_f(gG);
        float c1v = ig * cd - fj[j];
        c1[j] = c1v;
        h1w[j] = f2bf(og * tanh_f(c1v));
      }
      llc_store_4rows(h1his + ((size_t)(s & (RDEPTH - 1)) * BATCH + m0 + q * 4) * 512 + hcol,
                      h1w[0], h1w[1], h1w[2], h1w[3]);
      ushort4 hw;
      hw.x = f2bf(c1[0]); hw.y = f2bf(c1[1]); hw.z = f2bf(c1[2]); hw.w = f2bf(c1[3]);
      *(ushort4*)(HI + ((size_t)((s & (KHIST - 1)) * 16 + rg) * 16 + r16) * 4) = hw;
      drain_vm();                          // own publishes acked at LLC
      if (lane == 0) {
        int old = atomicAdd(dctr, 1);      // ds_add_rtn, monotone across steps
        if (old == 4 * s + 3)              // 4th wave this step -> publish flag
          flag_st_llc(aFlags + hs, s + 1);
      }
    }
  } else {
    // ---- B block ----
    unsigned short* WB = (unsigned short*)lds;                 // [64][1032]
    float* EX = (float*)(lds + 64 * WB_STRIDE * 2);            // exch [4 mi][4 g][64 lane][4]
    for (int idx = tid; idx < 64 * 128; idx += 512) {
      int rowi = idx >> 7, kc = idx & 127;
      int g = rowi >> 4, c = rowi & 15;
      const unsigned short* src = W2 + ((size_t)(g * 512 + hs * 16 + c)) * 1024 + kc * 8;
      *(short8*)(WB + rowi * WB_STRIDE + kc * 8) = *(const short8*)src;
    }
    const int mi = wv >> 1, kh = wv & 1;
    const int m0 = bs * 64 + mi * 16;
    float c2r[4] = {0.f, 0.f, 0.f, 0.f};
    int lenr[4];
    float bBr[4];
    #pragma unroll
    for (int j = 0; j < 4; ++j) lenr[j] = length[m0 + q * 4 + j];
    #pragma unroll
    for (int g = 0; g < 4; ++g) bBr[g] = bB[g * 512 + hcol];
    __syncthreads();

    for (int t = 0; t < T_STEPS; ++t) {
      // per-wave poll
      if (lane < 32) {
        const int* f = aFlags + lane;
        while (flag_ld_llc(f) < t + 1) __builtin_amdgcn_s_sleep(1);   // A done t
      } else if (t > 0) {
        const int* f = bFlags + (lane - 32);
        while (flag_ld_llc(f) < t) __builtin_amdgcn_s_sleep(1);       // B peers done t-1
      }
      floatx4 acc[4];
      #pragma unroll
      for (int g = 0; g < 4; ++g) acc[g] = (floatx4){0.f, 0.f, 0.f, 0.f};
      bool doit = !(kh == 1 && t == 0);
      if (doit) {
        const unsigned short* ab;
        if (kh == 0)
          ab = h1his + ((size_t)(t & (RDEPTH - 1)) * BATCH + m0 + r16) * 512 + q * 8;
        else
          ab = h2his + ((size_t)((t - 1) & (RDEPTH - 1)) * BATCH + m0 + r16) * 512 + q * 8;
        short8 af[16];
        llc_load_1k(ab, af);
        #pragma unroll
        for (int kk = 0; kk < 16; ++kk) {
          #pragma unroll
          for (int g = 0; g < 4; ++g) {
            short8 b = *(const short8*)(WB + (size_t)(g * 16 + r16) * WB_STRIDE + kh * 512 + kk * 32 + q * 8);
            acc[g] = __builtin_amdgcn_mfma_f32_16x16x32_bf16(af[kk], b, acc[g], 0, 0, 0);
          }
        }
      }
      if (kh == 1) {
        #pragma unroll
        for (int g = 0; g < 4; ++g)
          *(floatx4*)(EX + ((size_t)(mi * 4 + g) * 64 + lane) * 4) = acc[g];
      }
      __syncthreads();
      if (kh == 0) {
        #pragma unroll
        for (int g = 0; g < 4; ++g)
          acc[g] += *(const floatx4*)(EX + ((size_t)(mi * 4 + g) * 64 + lane) * 4);
        unsigned short h2w[4];
        #pragma unroll
        for (int j = 0; j < 4; ++j) {
          int row = m0 + q * 4 + j;
          float gi = acc[0][j] + bBr[0];
          float gf = acc[1][j] + bBr[1];
          float gg = acc[2][j] + bBr[2];
          float go = acc[3][j] + bBr[3];
          float c2n = sigm(gf) * c2r[j] + sigm(gi) * tanh_f(gg);
          c2r[j] = c2n;
          float h2n = tanh_f(sigm(go) * tanh_f(c2n));
          h2w[j] = f2bf(h2n);
          if (lenr[j] == t) sel[(size_t)row * 512 + hcol] = h2n;
        }
        llc_store_4rows(h2his + ((size_t)(t & (RDEPTH - 1)) * BATCH + m0 + q * 4) * 512 + hcol,
                        h2w[0], h2w[1], h2w[2], h2w[3]);
      }
      drain_vm();
      __syncthreads();
      if (tid == 0)
        flag_st_llc(bFlags + hs, t + 1);
    }
  }
}

// ---------------- output head ----------------
__global__ void out_head_kernel(const float* __restrict__ sel, const float* __restrict__ Wout,
                                const float* __restrict__ bout, float* __restrict__ out) {
  int b = blockIdx.x, lane = threadIdx.x;   // 256 blocks x 64 threads
  float acc[5] = {0.f, 0.f, 0.f, 0.f, 0.f};
  for (int j = lane; j < HDIM; j += 64) {
    float x = sel[(size_t)b * HDIM + j];
    #pragma unroll
    for (int o = 0; o < 5; ++o) acc[o] += x * Wout[o * HDIM + j];
  }
  #pragma unroll
  for (int o = 0; o < 5; ++o)
    for (int off = 32; off > 0; off >>= 1) acc[o] += __shfl_down(acc[o], off);
  if (lane == 0) {
    float v[5]; float m = -1e30f;
    #pragma unroll
    for (int o = 0; o < 5; ++o) { v[o] = acc[o] + bout[o]; m = fmaxf(m, v[o]); }
    float s = 0.f;
    #pragma unroll
    for (int o = 0; o < 5; ++o) s += __expf(v[o] - m);
    float l = logf(s) + m;
    #pragma unroll
    for (int o = 0; o < 5; ++o) out[b * 5 + o] = v[o] - l;
  }
}

// ---------------- launch ----------------
extern "C" void kernel_launch(void* const* d_in, const int* in_sizes, int n_in,
                              void* d_out, int out_size, void* d_ws, size_t ws_size,
                              hipStream_t stream) {
  const float* x      = (const float*)d_in[0];
  const int*   length = (const int*)d_in[1];
  const float* b_d    = (const float*)d_in[2];
  const float* W_mih  = (const float*)d_in[3];
  const float* W_mhh  = (const float*)d_in[4];
  const float* b_mih  = (const float*)d_in[5];
  const float* b_mhh  = (const float*)d_in[6];
  const float* W_ih   = (const float*)d_in[7];
  const float* W_hh   = (const float*)d_in[8];
  const float* b_ih   = (const float*)d_in[9];
  const float* b_hh   = (const float*)d_in[10];
  const float* W_out  = (const float*)d_in[11];
  const float* b_out  = (const float*)d_in[12];
  float* out = (float*)d_out;

  char* ws = (char*)d_ws;
  size_t off = 0;
  auto take = [&](size_t bytes) -> char* {
    char* p = ws + off;
    off += (bytes + 255) & ~(size_t)255;
    return p;
  };

  unsigned short* Xb     = (unsigned short*)take((size_t)T_STEPS * BATCH * IDIM * 2);
  unsigned short* Wmih_b = (unsigned short*)take(1536 * 512 * 2);
  unsigned short* Wmhh_b = (unsigned short*)take(1536 * 512 * 2);
  unsigned short* W2_b   = (unsigned short*)take(2048 * 1024 * 2);
  float* bA  = (float*)take(1536 * 4);
  float* bB  = (float*)take(2048 * 4);
  float* wd2 = (float*)take(KHIST * HDIM * 4);
  unsigned short* h1his = (unsigned short*)take((size_t)RDEPTH * BATCH * 512 * 2);
  unsigned short* h2his = (unsigned short*)take((size_t)RDEPTH * BATCH * 512 * 2);
  float* sel = (float*)take((size_t)BATCH * HDIM * 4);
  int* counters = (int*)take(8192);
  unsigned short* GXh = (unsigned short*)take((size_t)T_STEPS * BATCH * 1536 * 2);
  if (off > ws_size) return;  // workspace too small -> loud validation failure

  prep_all<<<PREP_BLOCKS, 256, 0, stream>>>(x, W_mih, W_mhh, W_ih, W_hh,
                                            b_d, b_mih, b_mhh, b_ih, b_hh,
                                            Xb, Wmih_b, Wmhh_b, W2_b, wd2, bA, bB, counters);
  gx_gemm_kernel<<<dim3(1536 / 64, T_STEPS * BATCH / 64), 256, 0, stream>>>(Xb, Wmih_b, bA, GXh);

  hipFuncSetAttribute((const void*)recurrent2, hipFuncAttributeMaxDynamicSharedMemorySize, LDS_BYTES);
  void* kargs[] = { (void*)&GXh, (void*)&Wmhh_b, (void*)&W2_b, (void*)&bB, (void*)&wd2,
                    (void*)&h1his, (void*)&h2his, (void*)&sel, (void*)&length,
                    (void*)&counters };
  hipLaunchCooperativeKernel((void*)recurrent2, dim3(256), dim3(512), kargs, LDS_BYTES, stream);

  out_head_kernel<<<BATCH, 64, 0, stream>>>(sel, W_out, b_out, out);
}

// Round 10
// 1582.863 us; speedup vs baseline: 1.1273x; 1.0554x over previous
//
#include <hip/hip_runtime.h>
#include <hip/hip_cooperative_groups.h>
#include <cstdint>
#include <cstddef>

typedef __attribute__((ext_vector_type(8))) short short8;   // 8 bf16 (4 VGPRs) MFMA frag
typedef __attribute__((ext_vector_type(4))) float floatx4;  // MFMA accumulator

#define T_STEPS 128
#define BATCH   256
#define IDIM    512
#define HDIM    512
#define KHIST   32
#define RDEPTH  16

// LDS layout
#define WA_STRIDE 520      // 512 + 8 pad
#define WB_STRIDE 1032     // 1024 + 8 pad
#define LDS_BYTES 148480   // B: WB 64*1032*2 + EX 16384; A: 49920 + 65536

__device__ __forceinline__ unsigned short f2bf(float x) {
  union { float f; unsigned u; } v; v.f = x;
  unsigned r = v.u + 0x7fffu + ((v.u >> 16) & 1u);   // RNE
  return (unsigned short)(r >> 16);
}
__device__ __forceinline__ float bf2f(unsigned short s) {
  union { unsigned u; float f; } v; v.u = ((unsigned)s) << 16; return v.f;
}
__device__ __forceinline__ float sigm(float x) { return 1.0f / (1.0f + __expf(-x)); }
__device__ __forceinline__ float tanh_f(float x) {
  float ax = fabsf(x);
  float e = __expf(-2.0f * ax);
  float t = (1.0f - e) / (1.0f + e);
  return x < 0.0f ? -t : t;
}

// ---- LLC-coherent exchange (round-6 proven protocol, no fences) ----
__device__ __forceinline__ void llc_load_1k(const unsigned short* p, short8* r) {
  asm volatile(
    "global_load_dwordx4 %0,  %16, off sc0 sc1\n\t"
    "global_load_dwordx4 %1,  %16, off offset:64 sc0 sc1\n\t"
    "global_load_dwordx4 %2,  %16, off offset:128 sc0 sc1\n\t"
    "global_load_dwordx4 %3,  %16, off offset:192 sc0 sc1\n\t"
    "global_load_dwordx4 %4,  %16, off offset:256 sc0 sc1\n\t"
    "global_load_dwordx4 %5,  %16, off offset:320 sc0 sc1\n\t"
    "global_load_dwordx4 %6,  %16, off offset:384 sc0 sc1\n\t"
    "global_load_dwordx4 %7,  %16, off offset:448 sc0 sc1\n\t"
    "global_load_dwordx4 %8,  %16, off offset:512 sc0 sc1\n\t"
    "global_load_dwordx4 %9,  %16, off offset:576 sc0 sc1\n\t"
    "global_load_dwordx4 %10, %16, off offset:640 sc0 sc1\n\t"
    "global_load_dwordx4 %11, %16, off offset:704 sc0 sc1\n\t"
    "global_load_dwordx4 %12, %16, off offset:768 sc0 sc1\n\t"
    "global_load_dwordx4 %13, %16, off offset:832 sc0 sc1\n\t"
    "global_load_dwordx4 %14, %16, off offset:896 sc0 sc1\n\t"
    "global_load_dwordx4 %15, %16, off offset:960 sc0 sc1\n\t"
    "s_waitcnt vmcnt(0)"
    : "=&v"(r[0]), "=&v"(r[1]), "=&v"(r[2]), "=&v"(r[3]),
      "=&v"(r[4]), "=&v"(r[5]), "=&v"(r[6]), "=&v"(r[7]),
      "=&v"(r[8]), "=&v"(r[9]), "=&v"(r[10]), "=&v"(r[11]),
      "=&v"(r[12]), "=&v"(r[13]), "=&v"(r[14]), "=&v"(r[15])
    : "v"(p)
    : "memory");
}
__device__ __forceinline__ void llc_store_4rows(unsigned short* p,
                                                unsigned short a, unsigned short b,
                                                unsigned short c, unsigned short d) {
  asm volatile(
    "global_store_short %4, %0, off sc0 sc1\n\t"
    "global_store_short %4, %1, off offset:1024 sc0 sc1\n\t"
    "global_store_short %4, %2, off offset:2048 sc0 sc1\n\t"
    "global_store_short %4, %3, off offset:3072 sc0 sc1"
    :: "v"((unsigned)a), "v"((unsigned)b), "v"((unsigned)c), "v"((unsigned)d), "v"(p)
    : "memory");
}
__device__ __forceinline__ int flag_ld_llc(const int* p) {
  int v; asm volatile("global_load_dword %0, %1, off sc0 sc1\n\ts_waitcnt vmcnt(0)"
                      : "=v"(v) : "v"(p) : "memory"); return v;
}
__device__ __forceinline__ void flag_st_llc(int* p, int v) {
  asm volatile("global_store_dword %0, %1, off sc0 sc1" :: "v"(p), "v"(v) : "memory");
}
__device__ __forceinline__ void drain_vm() {
  asm volatile("s_waitcnt vmcnt(0)" ::: "memory");
}

// ---------------- single fused prep kernel ----------------
#define PREP_BLOCKS 19992
__global__ __launch_bounds__(256) void prep_all(
    const float* __restrict__ x, const float* __restrict__ Wmih, const float* __restrict__ Wmhh,
    const float* __restrict__ Wih, const float* __restrict__ Whh,
    const float* __restrict__ b_d, const float* __restrict__ b_mih, const float* __restrict__ b_mhh,
    const float* __restrict__ b_ih, const float* __restrict__ b_hh,
    unsigned short* __restrict__ Xb, unsigned short* __restrict__ Wmih_b,
    unsigned short* __restrict__ Wmhh_b, unsigned short* __restrict__ W2,
    float* __restrict__ wd2, float* __restrict__ bA, float* __restrict__ bB,
    int* __restrict__ counters) {
  const int blk = blockIdx.x, tid = threadIdx.x;
  if (blk < 16384) {
    int i = blk * 256 + tid;
    float4 v = reinterpret_cast<const float4*>(x)[i];
    ushort4 o; o.x = f2bf(v.x); o.y = f2bf(v.y); o.z = f2bf(v.z); o.w = f2bf(v.w);
    reinterpret_cast<ushort4*>(Xb)[i] = o;
  } else if (blk < 17152) {
    int i = (blk - 16384) * 256 + tid;
    float4 v = reinterpret_cast<const float4*>(Wmih)[i];
    ushort4 o; o.x = f2bf(v.x); o.y = f2bf(v.y); o.z = f2bf(v.z); o.w = f2bf(v.w);
    reinterpret_cast<ushort4*>(Wmih_b)[i] = o;
  } else if (blk < 17920) {
    int i = (blk - 17152) * 256 + tid;
    float4 v = reinterpret_cast<const float4*>(Wmhh)[i];
    ushort4 o; o.x = f2bf(v.x); o.y = f2bf(v.y); o.z = f2bf(v.z); o.w = f2bf(v.w);
    reinterpret_cast<ushort4*>(Wmhh_b)[i] = o;
  } else if (blk < 19968) {
    int i4 = (blk - 17920) * 256 + tid;
    int i = i4 * 4; int n = i >> 10; int k = i & 1023;
    float4 v = (k < 512) ? reinterpret_cast<const float4*>(Wih + n * 512 + k)[0]
                         : reinterpret_cast<const float4*>(Whh + n * 512 + (k - 512))[0];
    ushort4 o; o.x = f2bf(v.x); o.y = f2bf(v.y); o.z = f2bf(v.z); o.w = f2bf(v.w);
    reinterpret_cast<ushort4*>(W2 + i)[0] = o;
  } else if (blk < 19984) {
    int t = (blk - 19968) * 256 + tid;
    if (t < 512) {
      float d = 0.5f * sigm(b_d[t]);
      float c = 1.0f;
      for (int i = 0; i < KHIST; ++i) {
        c *= ((float)i - d) / ((float)i + 1.0f);
        wd2[i * HDIM + t] = c;
      }
    } else if (t < 2048) {
      int n = t - 512;
      bA[n] = b_mih[n] + b_mhh[n];
    } else {
      int n = t - 2048;
      bB[n] = b_ih[n] + b_hh[n];
    }
  } else {
    int i = (blk - 19984) * 256 + tid;
    counters[i] = 0;
  }
}

// ---------------- input-projection GEMM, A-stationary LDS tiling ----------------
// 512 blocks x 64 rows. X-tile (64x512 bf16, stride 520) staged in LDS once;
// loop over all 24 column-chunks streaming the 1.5MB weight from per-XCD L2
// (shared by ~64 blocks/XCD -> HBM reads it once). Xb read once from HBM.
__global__ __launch_bounds__(256) void gx_gemm_kernel(const unsigned short* __restrict__ Xb,
                                                      const unsigned short* __restrict__ Wb,
                                                      const float* __restrict__ bA,
                                                      unsigned short* __restrict__ GXh) {
  __shared__ unsigned short XA[64 * WA_STRIDE];    // 66.6 KB -> 2 blocks/CU
  const int lane = threadIdx.x & 63;
  const int wave = threadIdx.x >> 6;
  const int q = lane >> 4, r16 = lane & 15;
  const int m0 = blockIdx.x * 64;
  for (int idx = threadIdx.x; idx < 64 * 64; idx += 256) {
    int r = idx >> 6, c = idx & 63;
    *(short8*)(XA + r * WA_STRIDE + c * 8) =
        *(const short8*)(Xb + (size_t)(m0 + r) * IDIM + c * 8);
  }
  __syncthreads();
  const unsigned short* arow = XA + (wave * 16 + r16) * WA_STRIDE;
  for (int n0 = 0; n0 < 1536; n0 += 64) {
    floatx4 acc[4];
    #pragma unroll
    for (int i = 0; i < 4; ++i) acc[i] = (floatx4){0.f, 0.f, 0.f, 0.f};
    #pragma unroll 4
    for (int k0 = 0; k0 < IDIM; k0 += 32) {
      short8 a = *(const short8*)(arow + k0 + q * 8);
      #pragma unroll
      for (int nt = 0; nt < 4; ++nt) {
        short8 b = *(const short8*)(Wb + (size_t)(n0 + nt * 16 + r16) * IDIM + k0 + q * 8);
        acc[nt] = __builtin_amdgcn_mfma_f32_16x16x32_bf16(a, b, acc[nt], 0, 0, 0);
      }
    }
    #pragma unroll
    for (int nt = 0; nt < 4; ++nt) {
      int col = n0 + nt * 16 + r16;
      float bias = bA[col];
      #pragma unroll
      for (int j = 0; j < 4; ++j) {
        int row = m0 + wave * 16 + q * 4 + j;
        GXh[(size_t)row * 1536 + col] = f2bf(acc[nt][j] + bias);
      }
    }
  }
}

// ---------------- async persistent recurrent kernel (r6 sync structure) ----------------
// 256 blocks: xcd=blk&7 -> chain bs=xcd>>1, role A/B by parity, hs=blk>>3.
// Protocol per step: wv0 polls (lanes 0-31 one producer flag each; 32-63 slack
// gates) -> __syncthreads -> compute -> drain_vm -> __syncthreads -> tid0 flag
// store. Exchange data moves only through sc0sc1 LLC ops; no fences anywhere.
__global__ __launch_bounds__(512, 1) void recurrent2(
    const unsigned short* __restrict__ GXh,    // (T*256 x 1536) bf16
    const unsigned short* __restrict__ Wmhh,   // (1536 x 512) bf16 N-major
    const unsigned short* __restrict__ W2,     // (2048 x 1024) bf16 N-major
    const float* __restrict__ bB,              // (2048)
    const float* __restrict__ wd2,             // (32 x 512)
    unsigned short* __restrict__ h1his,        // (16 x 256 x 512) bf16
    unsigned short* __restrict__ h2his,        // (16 x 256 x 512) bf16
    float* __restrict__ sel,                   // (256 x 512) fp32
    const int* __restrict__ length,
    int* __restrict__ counters) {              // aFlags at bs*64, bFlags at 1024+bs*64
  extern __shared__ char lds[];
  const int tid = threadIdx.x;
  const int lane = tid & 63;
  const int wv = tid >> 6;                 // 0..7
  const int q = lane >> 4, r16 = lane & 15;
  const int xcd = (int)blockIdx.x & 7;
  const int bs = xcd >> 1;
  const bool isA = (xcd & 1) == 0;
  const int hs = (int)blockIdx.x >> 3;
  const int hcol = hs * 16 + r16;
  int* aFlags = counters + bs * 64;
  int* bFlags = counters + 1024 + bs * 64;

  if (isA) {
    unsigned short* WA = (unsigned short*)lds;                        // [48][520]
    unsigned short* HI = (unsigned short*)(lds + 48 * WA_STRIDE * 2); // 64KB hist
    for (int idx = tid; idx < 48 * 64; idx += 512) {
      int rowi = idx >> 6, kc = idx & 63;
      int g = rowi >> 4, c = rowi & 15;
      const unsigned short* src = Wmhh + ((size_t)(g * 512 + hs * 16 + c)) * 512 + kc * 8;
      *(short8*)(WA + rowi * WA_STRIDE + kc * 8) = *(const short8*)src;
    }
    for (int idx = tid; idx < 4096; idx += 512)
      ((uint4*)HI)[idx] = (uint4){0, 0, 0, 0};
    float wdr[KHIST];
    #pragma unroll
    for (int l = 0; l < KHIST; ++l) wdr[l] = wd2[l * HDIM + hcol];
    __syncthreads();

    const int mi = wv & 3;
    const int m0 = bs * 64 + mi * 16;
    const int rg = mi * 4 + q;

    for (int s = 0; s < T_STEPS; ++s) {
      // GX prefetch (bf16 cached loads; complete during the poll)
      unsigned short gu[12];
      if (wv < 4) {
        #pragma unroll
        for (int j = 0; j < 4; ++j) {
          int row = m0 + q * 4 + j;
          size_t gidx = ((size_t)s * BATCH + row) * 1536 + hcol;
          gu[j]     = GXh[gidx];
          gu[4 + j] = GXh[gidx + 512];
          gu[8 + j] = GXh[gidx + 1024];
        }
      }
      if (wv == 0) {
        if (lane < 32) {
          if (s > 0) {
            const int* f = aFlags + lane;
            while (flag_ld_llc(f) < s) __builtin_amdgcn_s_sleep(1);
          }
        } else {
          int tgt = s - (RDEPTH - 1);
          if (tgt > 0) {
            const int* f = bFlags + (lane - 32);
            while (flag_ld_llc(f) < tgt) __builtin_amdgcn_s_sleep(1);
          }
        }
      }
      __syncthreads();
      if (wv < 4) {
        // frac-diff filter (wave-private LDS)
        float f0 = 0.f, f1 = 0.f, f2 = 0.f, f3 = 0.f;
        #pragma unroll
        for (int jj = 1; jj <= KHIST; ++jj) {
          int sl = (s - jj) & (KHIST - 1);
          ushort4 hv = *(const ushort4*)(HI + ((size_t)(sl * 16 + rg) * 16 + r16) * 4);
          float wc = wdr[jj - 1];
          f0 += wc * bf2f(hv.x); f1 += wc * bf2f(hv.y);
          f2 += wc * bf2f(hv.z); f3 += wc * bf2f(hv.w);
        }
        float fj[4] = {f0, f1, f2, f3};
        floatx4 acc[3];
        #pragma unroll
        for (int g = 0; g < 3; ++g) acc[g] = (floatx4){0.f, 0.f, 0.f, 0.f};
        if (s > 0) {
          const unsigned short* ab = h1his +
              ((size_t)((s - 1) & (RDEPTH - 1)) * BATCH + m0 + r16) * 512 + q * 8;
          short8 af[16];
          llc_load_1k(ab, af);
          #pragma unroll
          for (int kk = 0; kk < 16; ++kk) {
            #pragma unroll
            for (int g = 0; g < 3; ++g) {
              short8 b = *(const short8*)(WA + (size_t)(g * 16 + r16) * WA_STRIDE + kk * 32 + q * 8);
              acc[g] = __builtin_amdgcn_mfma_f32_16x16x32_bf16(af[kk], b, acc[g], 0, 0, 0);
            }
          }
        }
        float c1[4];
        unsigned short h1w[4];
        #pragma unroll
        for (int j = 0; j < 4; ++j) {
          float gI = bf2f(gu[j])     + acc[0][j];
          float gO = bf2f(gu[4 + j]) + acc[1][j];
          float gG = bf2f(gu[8 + j]) + acc[2][j];
          float ig = sigm(gI), og = sigm(gO), cd = tanh_f(gG);
          float c1v = ig * cd - fj[j];
          c1[j] = c1v;
          h1w[j] = f2bf(og * tanh_f(c1v));
        }
        llc_store_4rows(h1his + ((size_t)(s & (RDEPTH - 1)) * BATCH + m0 + q * 4) * 512 + hcol,
                        h1w[0], h1w[1], h1w[2], h1w[3]);
        ushort4 hw;
        hw.x = f2bf(c1[0]); hw.y = f2bf(c1[1]); hw.z = f2bf(c1[2]); hw.w = f2bf(c1[3]);
        *(ushort4*)(HI + ((size_t)((s & (KHIST - 1)) * 16 + rg) * 16 + r16) * 4) = hw;
      }
      drain_vm();
      __syncthreads();
      if (tid == 0)
        flag_st_llc(aFlags + hs, s + 1);
    }
  } else {
    // ---- B block ----
    unsigned short* WB = (unsigned short*)lds;                 // [64][1032]
    float* EX = (float*)(lds + 64 * WB_STRIDE * 2);            // exch [4 mi][4 g][64 lane][4]
    for (int idx = tid; idx < 64 * 128; idx += 512) {
      int rowi = idx >> 7, kc = idx & 127;
      int g = rowi >> 4, c = rowi & 15;
      const unsigned short* src = W2 + ((size_t)(g * 512 + hs * 16 + c)) * 1024 + kc * 8;
      *(short8*)(WB + rowi * WB_STRIDE + kc * 8) = *(const short8*)src;
    }
    const int mi = wv >> 1, kh = wv & 1;
    const int m0 = bs * 64 + mi * 16;
    float c2r[4] = {0.f, 0.f, 0.f, 0.f};
    int lenr[4];
    float bBr[4];
    #pragma unroll
    for (int j = 0; j < 4; ++j) lenr[j] = length[m0 + q * 4 + j];
    #pragma unroll
    for (int g = 0; g < 4; ++g) bBr[g] = bB[g * 512 + hcol];
    __syncthreads();

    for (int t = 0; t < T_STEPS; ++t) {
      if (wv == 0) {
        if (lane < 32) {
          const int* f = aFlags + lane;
          while (flag_ld_llc(f) < t + 1) __builtin_amdgcn_s_sleep(1);   // A done t
        } else if (t > 0) {
          const int* f = bFlags + (lane - 32);
          while (flag_ld_llc(f) < t) __builtin_amdgcn_s_sleep(1);       // B peers done t-1
        }
      }
      __syncthreads();
      floatx4 acc[4];
      #pragma unroll
      for (int g = 0; g < 4; ++g) acc[g] = (floatx4){0.f, 0.f, 0.f, 0.f};
      bool doit = !(kh == 1 && t == 0);
      if (doit) {
        const unsigned short* ab;
        if (kh == 0)
          ab = h1his + ((size_t)(t & (RDEPTH - 1)) * BATCH + m0 + r16) * 512 + q * 8;
        else
          ab = h2his + ((size_t)((t - 1) & (RDEPTH - 1)) * BATCH + m0 + r16) * 512 + q * 8;
        short8 af[16];
        llc_load_1k(ab, af);
        #pragma unroll
        for (int kk = 0; kk < 16; ++kk) {
          #pragma unroll
          for (int g = 0; g < 4; ++g) {
            short8 b = *(const short8*)(WB + (size_t)(g * 16 + r16) * WB_STRIDE + kh * 512 + kk * 32 + q * 8);
            acc[g] = __builtin_amdgcn_mfma_f32_16x16x32_bf16(af[kk], b, acc[g], 0, 0, 0);
          }
        }
      }
      if (kh == 1) {
        #pragma unroll
        for (int g = 0; g < 4; ++g)
          *(floatx4*)(EX + ((size_t)(mi * 4 + g) * 64 + lane) * 4) = acc[g];
      }
      __syncthreads();
      if (kh == 0) {
        #pragma unroll
        for (int g = 0; g < 4; ++g)
          acc[g] += *(const floatx4*)(EX + ((size_t)(mi * 4 + g) * 64 + lane) * 4);
        unsigned short h2w[4];
        #pragma unroll
        for (int j = 0; j < 4; ++j) {
          int row = m0 + q * 4 + j;
          float gi = acc[0][j] + bBr[0];
          float gf = acc[1][j] + bBr[1];
          float gg = acc[2][j] + bBr[2];
          float go = acc[3][j] + bBr[3];
          float c2n = sigm(gf) * c2r[j] + sigm(gi) * tanh_f(gg);
          c2r[j] = c2n;
          float h2n = tanh_f(sigm(go) * tanh_f(c2n));
          h2w[j] = f2bf(h2n);
          if (lenr[j] == t) sel[(size_t)row * 512 + hcol] = h2n;
        }
        llc_store_4rows(h2his + ((size_t)(t & (RDEPTH - 1)) * BATCH + m0 + q * 4) * 512 + hcol,
                        h2w[0], h2w[1], h2w[2], h2w[3]);
      }
      drain_vm();
      __syncthreads();
      if (tid == 0)
        flag_st_llc(bFlags + hs, t + 1);
    }
  }
}

// ---------------- output head ----------------
__global__ void out_head_kernel(const float* __restrict__ sel, const float* __restrict__ Wout,
                                const float* __restrict__ bout, float* __restrict__ out) {
  int b = blockIdx.x, lane = threadIdx.x;   // 256 blocks x 64 threads
  float acc[5] = {0.f, 0.f, 0.f, 0.f, 0.f};
  for (int j = lane; j < HDIM; j += 64) {
    float x = sel[(size_t)b * HDIM + j];
    #pragma unroll
    for (int o = 0; o < 5; ++o) acc[o] += x * Wout[o * HDIM + j];
  }
  #pragma unroll
  for (int o = 0; o < 5; ++o)
    for (int off = 32; off > 0; off >>= 1) acc[o] += __shfl_down(acc[o], off);
  if (lane == 0) {
    float v[5]; float m = -1e30f;
    #pragma unroll
    for (int o = 0; o < 5; ++o) { v[o] = acc[o] + bout[o]; m = fmaxf(m, v[o]); }
    float s = 0.f;
    #pragma unroll
    for (int o = 0; o < 5; ++o) s += __expf(v[o] - m);
    float l = logf(s) + m;
    #pragma unroll
    for (int o = 0; o < 5; ++o) out[b * 5 + o] = v[o] - l;
  }
}

// ---------------- launch ----------------
extern "C" void kernel_launch(void* const* d_in, const int* in_sizes, int n_in,
                              void* d_out, int out_size, void* d_ws, size_t ws_size,
                              hipStream_t stream) {
  const float* x      = (const float*)d_in[0];
  const int*   length = (const int*)d_in[1];
  const float* b_d    = (const float*)d_in[2];
  const float* W_mih  = (const float*)d_in[3];
  const float* W_mhh  = (const float*)d_in[4];
  const float* b_mih  = (const float*)d_in[5];
  const float* b_mhh  = (const float*)d_in[6];
  const float* W_ih   = (const float*)d_in[7];
  const float* W_hh   = (const float*)d_in[8];
  const float* b_ih   = (const float*)d_in[9];
  const float* b_hh   = (const float*)d_in[10];
  const float* W_out  = (const float*)d_in[11];
  const float* b_out  = (const float*)d_in[12];
  float* out = (float*)d_out;

  char* ws = (char*)d_ws;
  size_t off = 0;
  auto take = [&](size_t bytes) -> char* {
    char* p = ws + off;
    off += (bytes + 255) & ~(size_t)255;
    return p;
  };

  unsigned short* Xb     = (unsigned short*)take((size_t)T_STEPS * BATCH * IDIM * 2);
  unsigned short* Wmih_b = (unsigned short*)take(1536 * 512 * 2);
  unsigned short* Wmhh_b = (unsigned short*)take(1536 * 512 * 2);
  unsigned short* W2_b   = (unsigned short*)take(2048 * 1024 * 2);
  float* bA  = (float*)take(1536 * 4);
  float* bB  = (float*)take(2048 * 4);
  float* wd2 = (float*)take(KHIST * HDIM * 4);
  unsigned short* h1his = (unsigned short*)take((size_t)RDEPTH * BATCH * 512 * 2);
  unsigned short* h2his = (unsigned short*)take((size_t)RDEPTH * BATCH * 512 * 2);
  float* sel = (float*)take((size_t)BATCH * HDIM * 4);
  int* counters = (int*)take(8192);
  unsigned short* GXh = (unsigned short*)take((size_t)T_STEPS * BATCH * 1536 * 2);
  if (off > ws_size) return;  // workspace too small -> loud validation failure

  prep_all<<<PREP_BLOCKS, 256, 0, stream>>>(x, W_mih, W_mhh, W_ih, W_hh,
                                            b_d, b_mih, b_mhh, b_ih, b_hh,
                                            Xb, Wmih_b, Wmhh_b, W2_b, wd2, bA, bB, counters);
  gx_gemm_kernel<<<T_STEPS * BATCH / 64, 256, 0, stream>>>(Xb, Wmih_b, bA, GXh);

  hipFuncSetAttribute((const void*)recurrent2, hipFuncAttributeMaxDynamicSharedMemorySize, LDS_BYTES);
  void* kargs[] = { (void*)&GXh, (void*)&Wmhh_b, (void*)&W2_b, (void*)&bB, (void*)&wd2,
                    (void*)&h1his, (void*)&h2his, (void*)&sel, (void*)&length,
                    (void*)&counters };
  hipLaunchCooperativeKernel((void*)recurrent2, dim3(256), dim3(512), kargs, LDS_BYTES, stream);

  out_head_kernel<<<BATCH, 64, 0, stream>>>(sel, W_out, b_out, out);
}